// Round 6
// baseline (166.027 us; speedup 1.0000x reference)
//
#include <hip/hip_runtime.h>

#define HH 2048
#define WW 2048
#define NB 1024
#define TW 128
#define TH 32
#define NTX 16
#define NTY 64
#define NTILE 2048
#define CAP 32

typedef float f32x4 __attribute__((ext_vector_type(4)));
typedef unsigned long long u64;

// workspace layout (bytes)
#define OFF_COORD  0        // uint2[1024]
#define OFF_YINT   8192     // u64[64][16]
#define OFF_YFULL  16384
#define OFF_XINT   24576    // u64[16][16]
#define OFF_XFULL  26624
#define OFF_META   28672    // int2[2048]  {lastFull, cnt}   (cnt -1 = overflow)
#define OFF_ENT    45056    // uint4[2048][CAP]  {y1x1, y2x2, idx, 0}
// end ~1.07 MB

// ---- k1: axis-separable ballot masks ----
__global__ __launch_bounds__(256) void k1_masks(const float4* __restrict__ boxes,
                                                char* __restrict__ ws) {
    uint2* coordsW = (uint2*)(ws + OFF_COORD);
    const int tid = threadIdx.x, lane = tid & 63, wid = tid >> 6;
    const int bid = blockIdx.x;
    const bool isY = bid < NTY;
    const int lo0 = isY ? (bid * TH) : ((bid - NTY) * TW);
    const int ext = isY ? TH : TW;
    u64* intW  = isY ? ((u64*)(ws + OFF_YINT)  + bid * 16)
                     : ((u64*)(ws + OFF_XINT)  + (bid - NTY) * 16);
    u64* fullW = isY ? ((u64*)(ws + OFF_YFULL) + bid * 16)
                     : ((u64*)(ws + OFF_XFULL) + (bid - NTY) * 16);
    #pragma unroll
    for (int c = 0; c < 4; ++c) {
        float4 bx = boxes[c * 256 + tid];
        int y1 = max(0, (int)(bx.x * (float)HH));   // trunc == astype(int32)
        int x1 = max(0, (int)(bx.y * (float)WW));
        int y2 = min(HH, (int)(bx.z * (float)HH));
        int x2 = min(WW, (int)(bx.w * (float)WW));
        if (bid == 0)
            coordsW[c * 256 + tid] = make_uint2(((unsigned)y1 << 16) | (unsigned)x1,
                                                ((unsigned)y2 << 16) | (unsigned)x2);
        bool valid = (y1 < y2) && (x1 < x2);
        int a1 = isY ? y1 : x1, a2 = isY ? y2 : x2;
        bool bi = valid && (a1 < lo0 + ext) && (a2 > lo0);
        bool bf = valid && (a1 <= lo0) && (a2 >= lo0 + ext);
        u64 mi = __ballot(bi), mf = __ballot(bf);
        if (lane == 0) { intW[c * 4 + wid] = mi; fullW[c * 4 + wid] = mf; }
    }
}

// ---- k2: one thread per tile -> packed meta + uint4 candidate entries ----
__global__ __launch_bounds__(256) void k2_tiles(char* __restrict__ ws) {
    const uint2* coordsW = (const uint2*)(ws + OFF_COORD);
    const u64* yintW  = (const u64*)(ws + OFF_YINT);
    const u64* yfullW = (const u64*)(ws + OFF_YFULL);
    const u64* xintW  = (const u64*)(ws + OFF_XINT);
    const u64* xfullW = (const u64*)(ws + OFF_XFULL);
    int2* metaW = (int2*)(ws + OFF_META);
    uint4* entW = (uint4*)(ws + OFF_ENT);

    const int tix = blockIdx.x * 256 + threadIdx.x;   // 0..2047
    const int ty = tix >> 4, tx = tix & 15;

    u64 iw[16];
    #pragma unroll
    for (int c = 0; c < 16; ++c) iw[c] = yintW[ty * 16 + c] & xintW[tx * 16 + c];
    int lf = -1;
    #pragma unroll
    for (int c = 15; c >= 0; --c)
        if (lf < 0) {
            u64 fw = yfullW[ty * 16 + c] & xfullW[tx * 16 + c];
            if (fw) lf = c * 64 + 63 - __clzll(fw);
        }
    int j = 0;
    for (int c = 0; c < 16; ++c) {
        u64 m = iw[c];
        int d = lf - c * 64;
        if (d >= 63) m = 0;
        else if (d >= 0) m &= (~0ull) << (d + 1);
        while (m) {
            int b = c * 64 + __builtin_ctzll(m);
            m &= m - 1;
            if (j < CAP) {
                uint2 pc = coordsW[b];
                entW[tix * CAP + j] = make_uint4(pc.x, pc.y, (unsigned)b, 0u);
            }
            ++j;
        }
    }
    metaW[tix] = make_int2(lf, (j <= CAP) ? j : -1);
}

// ---- k3: fill-clone store engine. Grid-stride, pure linear order, no LDS ----
__global__ __launch_bounds__(256, 4) void k3_paint(const float4* __restrict__ boxes,
                                                   const char* __restrict__ ws,
                                                   float* __restrict__ out) {
    const int2* metaW = (const int2*)(ws + OFF_META);
    const uint4* entW = (const uint4*)(ws + OFF_ENT);
    const uint2* coordsW = (const uint2*)(ws + OFF_COORD);
    const float* bfp = (const float*)boxes;

    const int gid = blockIdx.x * 256 + threadIdx.x;   // 0..262143
    // 5*2^20 float4 total; 262144 threads -> 20 iterations, pure linear walk
    #pragma unroll 4
    for (int it = 0; it < 20; ++it) {
        const int idx = gid + (it << 18);             // float4 index
        const int ch  = idx >> 20;                    // 2^20 float4 per plane
        const int rem = idx & 0xFFFFF;
        const int y   = rem >> 9;                     // 512 float4 per row
        const int x0  = (rem & 511) << 2;
        const int tix = ((y >> 5) << 4) | (x0 >> 7);

        int2 mc = metaW[tix];
        int lf = mc.x, cnt = mc.y;
        int f0 = lf, f1 = lf, f2 = lf, f3 = lf;
        if (cnt >= 0) {
            const uint4* eb = entW + tix * CAP;
            for (int j = 0; j < cnt; ++j) {
                uint4 e = eb[j];
                int by1 = (int)(e.x >> 16), bx1 = (int)(e.x & 0xffffu);
                int by2 = (int)(e.y >> 16), bx2 = (int)(e.y & 0xffffu);
                if (y >= by1 && y < by2) {
                    if (bx1 <= x0 && bx2 >= x0 + 4) {
                        f0 = f1 = f2 = f3 = (int)e.z;      // chunk fully covered
                    } else {
                        int bidx = (int)e.z;
                        if (x0     >= bx1 && x0     < bx2) f0 = bidx;
                        if (x0 + 1 >= bx1 && x0 + 1 < bx2) f1 = bidx;
                        if (x0 + 2 >= bx1 && x0 + 2 < bx2) f2 = bidx;
                        if (x0 + 3 >= bx1 && x0 + 3 < bx2) f3 = bidx;
                    }
                }
            }
        } else {
            // overflow fallback (astronomically rare)
            for (int b = lf + 1; b < NB; ++b) {
                uint2 pc = coordsW[b];
                int by1 = (int)(pc.x >> 16), bx1 = (int)(pc.x & 0xffffu);
                int by2 = (int)(pc.y >> 16), bx2 = (int)(pc.y & 0xffffu);
                if (y >= by1 && y < by2) {
                    if (x0     >= bx1 && x0     < bx2) f0 = b;
                    if (x0 + 1 >= bx1 && x0 + 1 < bx2) f1 = b;
                    if (x0 + 2 >= bx1 && x0 + 2 < bx2) f2 = b;
                    if (x0 + 3 >= bx1 && x0 + 3 < bx2) f3 = b;
                }
            }
        }

        f32x4 v;
        if (f0 == f1 && f1 == f2 && f2 == f3) {
            float val = (f0 < 0) ? 0.f : ((ch == 0) ? 1.f : bfp[f0 * 4 + (ch - 1)]);
            v = (f32x4){val, val, val, val};
        } else {
            v.x = (f0 < 0) ? 0.f : ((ch == 0) ? 1.f : bfp[f0 * 4 + (ch - 1)]);
            v.y = (f1 < 0) ? 0.f : ((ch == 0) ? 1.f : bfp[f1 * 4 + (ch - 1)]);
            v.z = (f2 < 0) ? 0.f : ((ch == 0) ? 1.f : bfp[f2 * 4 + (ch - 1)]);
            v.w = (f3 < 0) ? 0.f : ((ch == 0) ? 1.f : bfp[f3 * 4 + (ch - 1)]);
        }
        *(f32x4*)(out + ((size_t)idx << 2)) = v;      // wave = 1KB contiguous, linear
    }
}

extern "C" void kernel_launch(void* const* d_in, const int* in_sizes, int n_in,
                              void* d_out, int out_size, void* d_ws, size_t ws_size,
                              hipStream_t stream) {
    const float4* boxes = (const float4*)d_in[0];
    float* out = (float*)d_out;
    char* ws = (char*)d_ws;
    k1_masks<<<dim3(NTY + NTX), dim3(256), 0, stream>>>(boxes, ws);
    k2_tiles<<<dim3(NTILE / 256), dim3(256), 0, stream>>>(ws);
    k3_paint<<<dim3(1024), dim3(256), 0, stream>>>(boxes, ws, out);
}

// Round 7
// 118.908 us; speedup vs baseline: 1.3963x; 1.3963x over previous
//
#include <hip/hip_runtime.h>

#define HH 2048
#define WW 2048
#define NB 1024
#define SW 128
#define NSTRIP 16
#define BANDH 4
#define CAP 24   // per-strip pruned candidates (128x4 region, avg ~1-2; fallback if over)

typedef float f32x4 __attribute__((ext_vector_type(4)));
typedef unsigned long long u64;

// SINGLE kernel (each extra dispatch costs ~10-12us of graph gap — measured
// R0 vs R5/R6). Block = (channel, 4-row band) -> 32KB contiguous store range;
// grid walks the 84MB output linearly (fill-shaped). Candidate lists built
// per block in LDS (R6 proved L2-resident lists are latency-death: 70.5us,
// VALUBusy 22%). cnt==0 strips (majority) take a zero-dependency broadcast
// path so store issue runs fill-like. 8 blocks/CU for deep store queues.

__global__ __launch_bounds__(256, 8) void paint_kernel(const float4* __restrict__ boxes,
                                                       float* __restrict__ out) {
    __shared__ uint2 coordL[NB];                 // 8KB: packed pixel coords
    __shared__ u64 imS[NSTRIP][4][4];            // 2KB: intersect ballots [strip][chunk][wave]
    __shared__ u64 fmS[NSTRIP][4][4];            // 2KB: full-cover ballots
    __shared__ uint2 entL[NSTRIP][CAP];          // 3KB: pruned candidate coords
    __shared__ short idxL[NSTRIP][CAP];          // .75KB: candidate indices
    __shared__ int2 metaL[NSTRIP];               // {lastFull, cnt} (-1 = overflow)
    __shared__ float vlfL[NSTRIP];               // lastFull's value for this channel

    const int tid = threadIdx.x, lane = tid & 63, wid = tid >> 6;
    const int job  = blockIdx.x;                 // natural order = linear output walk
    const int ch   = job >> 9;                   // 0..4
    const int band = job & 511;                  // 0..511
    const int y0   = band * BANDH;
    const float* bfp = (const float*)boxes;

    // ---- prologue: separable ballots for the 16 strips of THIS band ----
    #pragma unroll
    for (int c = 0; c < 4; ++c) {
        float4 bx = boxes[c * 256 + tid];
        int y1 = max(0, (int)(bx.x * (float)HH));   // trunc == astype(int32)
        int x1 = max(0, (int)(bx.y * (float)WW));
        int y2 = min(HH, (int)(bx.z * (float)HH));
        int x2 = min(WW, (int)(bx.w * (float)WW));
        coordL[c * 256 + tid] = make_uint2(((unsigned)y1 << 16) | (unsigned)x1,
                                           ((unsigned)y2 << 16) | (unsigned)x2);
        bool valid = (y1 < y2) && (x1 < x2);
        bool yint  = valid && (y1 < y0 + BANDH) && (y2 > y0);
        bool yfull = valid && (y1 <= y0) && (y2 >= y0 + BANDH);
        int ilo = x1 >> 7, ihi = min(NSTRIP, (x2 + SW - 1) >> 7);
        unsigned imask = (yint && ihi > ilo) ? (((1u << (ihi - ilo)) - 1u) << ilo) : 0u;
        int clo = (x1 + SW - 1) >> 7, chi = x2 >> 7;
        unsigned fmask = (yfull && chi > clo) ? (((1u << (chi - clo)) - 1u) << clo) : 0u;
        #pragma unroll
        for (int s = 0; s < NSTRIP; ++s) {
            u64 bi = __ballot((imask >> s) & 1u);
            u64 bf = __ballot((fmask >> s) & 1u);
            if (lane == 0) { imS[s][c][wid] = bi; fmS[s][c][wid] = bf; }
        }
    }
    __syncthreads();

    // ---- 16 leader threads: per-strip lastFull + pruned compaction ----
    if (tid < NSTRIP) {
        const int s = tid;
        int lf = -1;
        for (int c = 3; c >= 0 && lf < 0; --c)
            for (int w = 3; w >= 0 && lf < 0; --w) {
                u64 m = fmS[s][c][w];
                if (m) lf = c * 256 + w * 64 + 63 - __clzll(m);
            }
        int j = 0;
        for (int c = 0; c < 4; ++c)
            for (int w = 0; w < 4; ++w) {
                u64 m = imS[s][c][w];
                int base = c * 256 + w * 64;
                int d = lf - base;
                if (d >= 63) m = 0;
                else if (d >= 0) m &= (~0ull) << (d + 1);
                while (m) {
                    int b = base + __builtin_ctzll(m);
                    m &= m - 1;
                    if (j < CAP) { entL[s][j] = coordL[b]; idxL[s][j] = (short)b; }
                    ++j;
                }
            }
        metaL[s] = make_int2(lf, (j <= CAP) ? j : -1);
        vlfL[s] = (lf < 0) ? 0.f : ((ch == 0) ? 1.f : bfp[lf * 4 + (ch - 1)]);
    }
    __syncthreads();

    // ---- store phase: wave = one image row; 8 x 1KB contiguous wave stores ----
    const int y = y0 + wid;
    float* op = out + (size_t)ch * ((size_t)HH * WW) + (size_t)y * WW;

    #pragma unroll
    for (int k = 0; k < 8; ++k) {
        const int px0 = k * 256 + lane * 4;
        const int s = px0 >> 7;
        int2 mc = metaL[s];
        const int lf = mc.x, cnt = mc.y;
        f32x4 v;
        if (cnt == 0) {
            // zero-dependency broadcast path (majority of strips)
            float u = vlfL[s];
            v = (f32x4){u, u, u, u};
        } else {
            int f0 = lf, f1 = lf, f2 = lf, f3 = lf;
            if (cnt > 0) {
                for (int j = 0; j < cnt; ++j) {
                    uint2 pc = entL[s][j];
                    int bidx = idxL[s][j];
                    int by1 = (int)(pc.x >> 16), bx1 = (int)(pc.x & 0xffffu);
                    int by2 = (int)(pc.y >> 16), bx2 = (int)(pc.y & 0xffffu);
                    if (y >= by1 && y < by2) {
                        if (bx1 <= px0 && bx2 >= px0 + 4) {
                            f0 = f1 = f2 = f3 = bidx;       // chunk fully covered
                        } else {
                            if (px0     >= bx1 && px0     < bx2) f0 = bidx;
                            if (px0 + 1 >= bx1 && px0 + 1 < bx2) f1 = bidx;
                            if (px0 + 2 >= bx1 && px0 + 2 < bx2) f2 = bidx;
                            if (px0 + 3 >= bx1 && px0 + 3 < bx2) f3 = bidx;
                        }
                    }
                }
            } else {
                // overflow fallback (astronomically rare)
                for (int b = lf + 1; b < NB; ++b) {
                    uint2 pc = coordL[b];
                    int by1 = (int)(pc.x >> 16), bx1 = (int)(pc.x & 0xffffu);
                    int by2 = (int)(pc.y >> 16), bx2 = (int)(pc.y & 0xffffu);
                    if (y >= by1 && y < by2) {
                        if (px0     >= bx1 && px0     < bx2) f0 = b;
                        if (px0 + 1 >= bx1 && px0 + 1 < bx2) f1 = b;
                        if (px0 + 2 >= bx1 && px0 + 2 < bx2) f2 = b;
                        if (px0 + 3 >= bx1 && px0 + 3 < bx2) f3 = b;
                    }
                }
            }
            if (f0 == f1 && f1 == f2 && f2 == f3) {
                float u = (f0 < 0) ? 0.f : ((ch == 0) ? 1.f : bfp[f0 * 4 + (ch - 1)]);
                v = (f32x4){u, u, u, u};
            } else {
                v.x = (f0 < 0) ? 0.f : ((ch == 0) ? 1.f : bfp[f0 * 4 + (ch - 1)]);
                v.y = (f1 < 0) ? 0.f : ((ch == 0) ? 1.f : bfp[f1 * 4 + (ch - 1)]);
                v.z = (f2 < 0) ? 0.f : ((ch == 0) ? 1.f : bfp[f2 * 4 + (ch - 1)]);
                v.w = (f3 < 0) ? 0.f : ((ch == 0) ? 1.f : bfp[f3 * 4 + (ch - 1)]);
            }
        }
        *(f32x4*)(op + px0) = v;
    }
}

extern "C" void kernel_launch(void* const* d_in, const int* in_sizes, int n_in,
                              void* d_out, int out_size, void* d_ws, size_t ws_size,
                              hipStream_t stream) {
    const float4* boxes = (const float4*)d_in[0];
    float* out = (float*)d_out;
    dim3 grid(5 * 512);   // 2560 blocks = 8/CU; natural order = linear output walk
    dim3 block(256);
    paint_kernel<<<grid, block, 0, stream>>>(boxes, out);
}

// Round 8
// 104.401 us; speedup vs baseline: 1.5903x; 1.1390x over previous
//
#include <hip/hip_runtime.h>

#define HH 2048
#define WW 2048
#define NB 1024
#define BANDH 4
#define NSTRIP 16
#define CAP 32

typedef float f32x4 __attribute__((ext_vector_type(4)));

// Single kernel (each extra dispatch = ~12us graph gap, pinned by R6).
// Block = 4-row band x ALL 5 channels (80KB out) -> R0's prologue
// amortization with R7's contiguous stores (wave writes full 8KB rows).
// Ownership = MAX box index covering pixel (paint order == index order),
// so candidate lists are UNORDERED -> two-phase LDS-atomic prologue
// (atomicMax lastFull, pruned atomicAdd append); no ballots, no serial
// leader section (R7's regression), no 16-strip ballot storm.
// launch_bounds(256,4): 128 VGPR cap, no spill (R7's (256,8)=64 likely spilled).

__device__ __forceinline__ float box_val(int f, int ch, const float* bfp) {
    return (f < 0) ? 0.f : ((ch == 0) ? 1.f : bfp[f * 4 + ch - 1]);
}

__global__ __launch_bounds__(256, 4) void paint_kernel(const float4* __restrict__ boxes,
                                                       float* __restrict__ out) {
    __shared__ uint2 coordL[NB];           // 8KB (overflow fallback only)
    __shared__ uint4 entL[NSTRIP][CAP];    // 8KB {y1x1, y2x2, idx, -}
    __shared__ int lfS[NSTRIP];
    __shared__ int cntS[NSTRIP];
    __shared__ float vlfL[5][NSTRIP];      // lastFull value per channel

    const int tid = threadIdx.x, lane = tid & 63, wid = tid >> 6;
    const int y0 = blockIdx.x * BANDH;     // natural order = linear walk (R0/fill pattern)
    const float* bfp = (const float*)boxes;

    if (tid < NSTRIP) { lfS[tid] = -1; cntS[tid] = 0; }
    __syncthreads();

    // ---- phase 1: convert + stash coords + per-strip lastFull via atomicMax ----
    int ry1[4], rx1[4], ry2[4], rx2[4];
    #pragma unroll
    for (int c = 0; c < 4; ++c) {
        float4 bx = boxes[c * 256 + tid];
        int y1 = max(0, (int)(bx.x * (float)HH));   // trunc == astype(int32)
        int x1 = max(0, (int)(bx.y * (float)WW));
        int y2 = min(HH, (int)(bx.z * (float)HH));
        int x2 = min(WW, (int)(bx.w * (float)WW));
        ry1[c] = y1; rx1[c] = x1; ry2[c] = y2; rx2[c] = x2;
        coordL[c * 256 + tid] = make_uint2(((unsigned)y1 << 16) | (unsigned)x1,
                                           ((unsigned)y2 << 16) | (unsigned)x2);
        bool yfull = (y1 < y2) && (x1 < x2) && (y1 <= y0) && (y2 >= y0 + BANDH);
        if (yfull) {
            int b = c * 256 + tid;
            // strips fully covered in x: [ceil(x1/128), x2>>7)
            for (int s = (x1 + 127) >> 7; s < (x2 >> 7); ++s)
                atomicMax(&lfS[s], b);
        }
    }
    __syncthreads();

    // ---- phase 2: pruned UNORDERED append of intersecting candidates ----
    #pragma unroll
    for (int c = 0; c < 4; ++c) {
        int y1 = ry1[c], x1 = rx1[c], y2 = ry2[c], x2 = rx2[c];
        bool yint = (y1 < y2) && (x1 < x2) && (y1 < y0 + BANDH) && (y2 > y0);
        if (yint) {
            int b = c * 256 + tid;
            // strips intersected in x: [x1>>7, ceil(x2/128))
            for (int s = x1 >> 7; s < ((x2 + 127) >> 7); ++s) {
                if (b > lfS[s]) {
                    int pos = atomicAdd(&cntS[s], 1);
                    if (pos < CAP)
                        entL[s][pos] = make_uint4(((unsigned)y1 << 16) | (unsigned)x1,
                                                  ((unsigned)y2 << 16) | (unsigned)x2,
                                                  (unsigned)b, 0u);
                }
            }
        }
    }
    __syncthreads();

    // ---- finalize: lastFull values per channel; mark overflow ----
    if (tid < 80) {
        int s = tid & 15, ch = tid >> 4;
        int lf = lfS[s];
        vlfL[ch][s] = box_val(lf, ch, bfp);
        if (ch == 0 && cntS[s] > CAP) cntS[s] = -1;
    }
    __syncthreads();

    // ---- ownership: once per 4px chunk, shared across all 5 channels ----
    const int y = y0 + wid;                // wave = one image row
    int fnd[8][4];
    unsigned pureB = 0, uniB = 0;
    #pragma unroll
    for (int k = 0; k < 8; ++k) {
        const int px0 = k * 256 + lane * 4;
        const int s = px0 >> 7;
        const int lf = lfS[s];
        const int cnt = cntS[s];
        int f0 = lf, f1 = lf, f2 = lf, f3 = lf;
        if (cnt > 0) {
            for (int j = 0; j < cnt; ++j) {
                uint4 e = entL[s][j];
                int by1 = (int)(e.x >> 16), bx1 = (int)(e.x & 0xffffu);
                int by2 = (int)(e.y >> 16), bx2 = (int)(e.y & 0xffffu);
                int b = (int)e.z;
                if (y >= by1 && y < by2) {
                    if (bx1 <= px0 && bx2 >= px0 + 4) {
                        f0 = max(f0, b); f1 = max(f1, b);
                        f2 = max(f2, b); f3 = max(f3, b);
                    } else {
                        if (px0     >= bx1 && px0     < bx2) f0 = max(f0, b);
                        if (px0 + 1 >= bx1 && px0 + 1 < bx2) f1 = max(f1, b);
                        if (px0 + 2 >= bx1 && px0 + 2 < bx2) f2 = max(f2, b);
                        if (px0 + 3 >= bx1 && px0 + 3 < bx2) f3 = max(f3, b);
                    }
                }
            }
        } else if (cnt < 0) {
            // overflow fallback: ascending scan (order restores paint semantics)
            for (int b = lf + 1; b < NB; ++b) {
                uint2 pc = coordL[b];
                int by1 = (int)(pc.x >> 16), bx1 = (int)(pc.x & 0xffffu);
                int by2 = (int)(pc.y >> 16), bx2 = (int)(pc.y & 0xffffu);
                if (y >= by1 && y < by2) {
                    if (px0     >= bx1 && px0     < bx2) f0 = b;
                    if (px0 + 1 >= bx1 && px0 + 1 < bx2) f1 = b;
                    if (px0 + 2 >= bx1 && px0 + 2 < bx2) f2 = b;
                    if (px0 + 3 >= bx1 && px0 + 3 < bx2) f3 = b;
                }
            }
        }
        fnd[k][0] = f0; fnd[k][1] = f1; fnd[k][2] = f2; fnd[k][3] = f3;
        if (cnt == 0) pureB |= 1u << k;
        if (f0 == f1 && f1 == f2 && f2 == f3) uniB |= 1u << k;
    }

    // ---- stores: ch outer, k inner -> each wave writes 5 full 8KB rows ----
    #pragma unroll
    for (int ch = 0; ch < 5; ++ch) {
        float* op = out + (size_t)ch * ((size_t)HH * WW) + (size_t)y * WW;
        #pragma unroll
        for (int k = 0; k < 8; ++k) {
            const int px0 = k * 256 + lane * 4;
            const int s = px0 >> 7;
            f32x4 v;
            if ((pureB >> k) & 1u) {
                float u = vlfL[ch][s];            // zero-VMEM broadcast path
                v = (f32x4){u, u, u, u};
            } else if ((uniB >> k) & 1u) {
                float u = box_val(fnd[k][0], ch, bfp);
                v = (f32x4){u, u, u, u};
            } else {
                v.x = box_val(fnd[k][0], ch, bfp);
                v.y = box_val(fnd[k][1], ch, bfp);
                v.z = box_val(fnd[k][2], ch, bfp);
                v.w = box_val(fnd[k][3], ch, bfp);
            }
            *(f32x4*)(op + px0) = v;
        }
    }
}

extern "C" void kernel_launch(void* const* d_in, const int* in_sizes, int n_in,
                              void* d_out, int out_size, void* d_ws, size_t ws_size,
                              hipStream_t stream) {
    const float4* boxes = (const float4*)d_in[0];
    float* out = (float*)d_out;
    dim3 grid(HH / BANDH);   // 512 blocks, natural order
    dim3 block(256);
    paint_kernel<<<grid, block, 0, stream>>>(boxes, out);
}